// Round 1
// baseline (511.625 us; speedup 1.0000x reference)
//
#include <hip/hip_runtime.h>
#include <hip/hip_cooperative_groups.h>
#include <math.h>

namespace cg = cooperative_groups;

constexpr int V = 32000, H = 1024, E = 1024, B = 64, S = 128;
constexpr int KX = 2048;                      // xcat = [emb | context]

// d_out offsets (floats), return order: logprobs, h1, c1, attn_weights
constexpr long long OUT_H1   = (long long)B * V;      // 2048000
constexpr long long OUT_C1   = OUT_H1 + (long long)B * H;
constexpr long long OUT_ATTN = OUT_C1 + (long long)B * H;

// ws offsets (floats) — scores/ctxp regions retired (fused kernel), layout kept
constexpr long long WS_SCORES = 0;                                  // unused
constexpr long long WS_XCAT   = WS_SCORES + (long long)B * S;       // B*2048
constexpr long long WS_PART   = WS_XCAT + (long long)B * KX;        // 6*B*4096
constexpr long long WS_CTXP   = WS_PART + 6LL * B * 4096;           // unused
constexpr long long WS_PM     = WS_CTXP + 4LL * B * H;              // 64*512
constexpr long long WS_PL     = WS_PM + 64 * 512;                   // 64*512
constexpr long long WS_LC     = WS_PL + 64 * 512;                   // 64

typedef __attribute__((ext_vector_type(8))) short short8;
typedef __attribute__((ext_vector_type(4))) float f32x4;

__device__ __forceinline__ unsigned short f2bf(float f) {
  unsigned u = __float_as_uint(f);
  u += 0x7FFF + ((u >> 16) & 1);          // round-to-nearest-even
  return (unsigned short)(u >> 16);
}

__device__ __forceinline__ short8 pack8(float4 a, float4 b) {
  short8 s;
  s[0] = (short)f2bf(a.x); s[1] = (short)f2bf(a.y);
  s[2] = (short)f2bf(a.z); s[3] = (short)f2bf(a.w);
  s[4] = (short)f2bf(b.x); s[5] = (short)f2bf(b.y);
  s[6] = (short)f2bf(b.z); s[7] = (short)f2bf(b.w);
  return s;
}

// ---- MFMA GEMM body: dst[b, g0+g] (+bias) = sum_k W[g0+g, k0+k] X[b, k0+k] -
// 64(g) x 64(b) tile per block, bf16 16x16x32 MFMA, fp32->bf16 in registers.
// Software-pipelined: K-tile kt+1 global loads issued before MFMA phase of kt.
// LDS: bf16 tiles, row stride 64, 8-bf16 chunks XOR-swizzled by (row&7).
// If pm != nullptr: also emit per-block log-softmax partials over the 64
// g-rows (pm[b*512+blk] = max, pl[b*512+blk] = sum exp(v - max)).
__device__ __forceinline__ void gemm_body(
    const float* __restrict__ W, int ldw,
    const float* __restrict__ X, int ldx,
    int g0, int k0, int KC,
    float* __restrict__ dst, int ldo, const float* __restrict__ bias,
    float* __restrict__ pm, float* __restrict__ pl) {
  __shared__ __align__(16) unsigned short Wl[64 * 64];
  __shared__ __align__(16) unsigned short Xl[64 * 64];
  __shared__ float pmx[4][64];
  __shared__ float psm[4][64];
  int t = threadIdx.x;
  int lane = t & 63, wid = t >> 6;
  int n = lane & 15, quad = lane >> 4;
  // staging: 512 chunks (8 bf16) per tile, 2 per thread
  int r0 = t >> 3,          c0 = t & 7;
  int r1 = (t + 256) >> 3,  c1 = (t + 256) & 7;
  int ws0 = r0 * 64 + (c0 ^ (r0 & 7)) * 8;
  int ws1 = r1 * 64 + (c1 ^ (r1 & 7)) * 8;
  f32x4 acc[4] = {{0.f,0.f,0.f,0.f},{0.f,0.f,0.f,0.f},
                  {0.f,0.f,0.f,0.f},{0.f,0.f,0.f,0.f}};
  const float* wp0 = W + (long long)(g0 + r0) * ldw + k0 + c0 * 8;
  const float* wp1 = W + (long long)(g0 + r1) * ldw + k0 + c1 * 8;
  const float* xp0 = X + (long long)r0 * ldx + k0 + c0 * 8;
  const float* xp1 = X + (long long)r1 * ldx + k0 + c1 * 8;
  // prefetch K-tile 0
  float4 wa = ((const float4*)wp0)[0], wb = ((const float4*)wp0)[1];
  float4 wc = ((const float4*)wp1)[0], wd = ((const float4*)wp1)[1];
  float4 xa = ((const float4*)xp0)[0], xb = ((const float4*)xp0)[1];
  float4 xc = ((const float4*)xp1)[0], xd = ((const float4*)xp1)[1];

  for (int kt = 0; kt < KC; kt += 64) {
    __syncthreads();                       // prior compute's LDS reads done
    *(short8*)&Wl[ws0] = pack8(wa, wb);
    *(short8*)&Wl[ws1] = pack8(wc, wd);
    *(short8*)&Xl[ws0] = pack8(xa, xb);
    *(short8*)&Xl[ws1] = pack8(xc, xd);
    __syncthreads();
    if (kt + 64 < KC) {                    // issue next tile's loads now;
      int o = kt + 64;                     // consumed at next LDS write
      wa = *(const float4*)(wp0 + o); wb = *(const float4*)(wp0 + o + 4);
      wc = *(const float4*)(wp1 + o); wd = *(const float4*)(wp1 + o + 4);
      xa = *(const float4*)(xp0 + o); xb = *(const float4*)(xp0 + o + 4);
      xc = *(const float4*)(xp1 + o); xd = *(const float4*)(xp1 + o + 4);
    }
#pragma unroll
    for (int kc = 0; kc < 2; ++kc) {
      short8 af = *(const short8*)&Wl[(wid * 16 + n) * 64 +
                                      (((kc * 4 + quad) ^ (n & 7)) * 8)];
#pragma unroll
      for (int nt = 0; nt < 4; ++nt) {
        short8 bf = *(const short8*)&Xl[(nt * 16 + n) * 64 +
                                        (((kc * 4 + quad) ^ (n & 7)) * 8)];
        acc[nt] = __builtin_amdgcn_mfma_f32_16x16x32_bf16(af, bf, acc[nt], 0, 0, 0);
      }
    }
  }
  // epilogue: C/D layout col=lane&15 (b), row=quad*4+reg (g-local)
  int gl = wid * 16 + quad * 4;
  float bs[4] = {0.f, 0.f, 0.f, 0.f};
  if (bias) {
#pragma unroll
    for (int r = 0; r < 4; ++r) bs[r] = bias[g0 + gl + r];
  }
  float v[4][4];
#pragma unroll
  for (int nt = 0; nt < 4; ++nt) {
    int b = nt * 16 + n;
#pragma unroll
    for (int r = 0; r < 4; ++r) {
      v[nt][r] = acc[nt][r] + bs[r];
      dst[(long long)b * ldo + g0 + gl + r] = v[nt][r];
    }
  }
  if (pm) {
    // per-block log-softmax partials over this block's 64 rows, per b
    float tmax[4];
#pragma unroll
    for (int nt = 0; nt < 4; ++nt) {
      tmax[nt] = fmaxf(fmaxf(v[nt][0], v[nt][1]), fmaxf(v[nt][2], v[nt][3]));
      tmax[nt] = fmaxf(tmax[nt], __shfl_xor(tmax[nt], 16, 64));
      tmax[nt] = fmaxf(tmax[nt], __shfl_xor(tmax[nt], 32, 64));
    }
    if (lane < 16) {
#pragma unroll
      for (int nt = 0; nt < 4; ++nt) pmx[wid][nt * 16 + lane] = tmax[nt];
    }
    __syncthreads();
    float bmax[4], tsum[4];
#pragma unroll
    for (int nt = 0; nt < 4; ++nt) {
      bmax[nt] = fmaxf(fmaxf(pmx[0][nt * 16 + n], pmx[1][nt * 16 + n]),
                       fmaxf(pmx[2][nt * 16 + n], pmx[3][nt * 16 + n]));
      tsum[nt] = __expf(v[nt][0] - bmax[nt]) + __expf(v[nt][1] - bmax[nt]) +
                 __expf(v[nt][2] - bmax[nt]) + __expf(v[nt][3] - bmax[nt]);
      tsum[nt] += __shfl_xor(tsum[nt], 16, 64);
      tsum[nt] += __shfl_xor(tsum[nt], 32, 64);
    }
    if (lane < 16) {
#pragma unroll
      for (int nt = 0; nt < 4; ++nt) psm[wid][nt * 16 + lane] = tsum[nt];
    }
    __syncthreads();
    if (t < 64) {
      float M = fmaxf(fmaxf(pmx[0][t], pmx[1][t]), fmaxf(pmx[2][t], pmx[3][t]));
      float L = psm[0][t] + psm[1][t] + psm[2][t] + psm[3][t];
      pm[t * 512 + blockIdx.x] = M;
      pl[t * 512 + blockIdx.x] = L;
    }
  }
}

// gates: grid (64, 6). y<4: W_ih K-split 4; y>=4: W_hh K-split 2.
__global__ __launch_bounds__(256) void k_gates_mfma(
    const float* __restrict__ W_ih, const float* __restrict__ xcat,
    const float* __restrict__ W_hh, const float* __restrict__ h0,
    float* __restrict__ part) {
  int y = blockIdx.y;
  if (y < 4)
    gemm_body(W_ih, KX, xcat, KX, blockIdx.x * 64, y * 512, 512,
              part + (long long)y * B * 4096, 4096, nullptr, nullptr, nullptr);
  else
    gemm_body(W_hh, H, h0, H, blockIdx.x * 64, (y - 4) * 512, 512,
              part + (long long)y * B * 4096, 4096, nullptr, nullptr, nullptr);
}

// ---- K_ATTN: fused scores + softmax + context + xcat. One block per b. -----
// enc[b] slice (512 KB) is read twice per block: once from HBM (scores),
// once L2-hot (context). Replaces 4 kernels (scores/softmax/ctx/xcat).
__global__ __launch_bounds__(256) void k_attn(
    const float* __restrict__ enc, const float* __restrict__ h0,
    const float* __restrict__ attn_w, const float* __restrict__ attn_b,
    const float* __restrict__ emb, const int* __restrict__ idx,
    float* __restrict__ attn_out, float* __restrict__ xcat) {
  __shared__ float red[256];
  __shared__ float aw[S];                        // raw scores, then weights
  int b = blockIdx.x, t = threadIdx.x;
  int lane = t & 63, wv = t >> 6;
  // h_part = dot(h0[b], attn_w[:H]) + attn_b
  const float4* h4  = (const float4*)(h0 + (long long)b * H);
  const float4* w4l = (const float4*)attn_w;
  float4 hv = h4[t], wvv = w4l[t];
  float p = hv.x * wvv.x + hv.y * wvv.y + hv.z * wvv.z + hv.w * wvv.w;
#pragma unroll
  for (int m = 32; m; m >>= 1) p += __shfl_xor(p, m, 64);
  if (lane == 0) red[wv] = p;
  __syncthreads();
  float hp = red[0] + red[1] + red[2] + red[3] + attn_b[0];
  // attn_w[H:] resident in registers for the scores loop
  const float4* w4h = (const float4*)(attn_w + H);
  float4 wreg[4];
#pragma unroll
  for (int j = 0; j < 4; ++j) wreg[j] = w4h[lane + 64 * j];
  __syncthreads();                               // red[0..3] consumed
  // scores: wave wv owns s = wv*32 + i (coalesced 1 KB row segments)
  for (int i = 0; i < 32; ++i) {
    int s = wv * 32 + i;
    const float4* e4 = (const float4*)(enc + (long long)(b * S + s) * H);
    float a = 0.f;
#pragma unroll
    for (int j = 0; j < 4; ++j) {
      float4 e = e4[lane + 64 * j];
      a += e.x * wreg[j].x + e.y * wreg[j].y + e.z * wreg[j].z + e.w * wreg[j].w;
    }
#pragma unroll
    for (int m = 32; m; m >>= 1) a += __shfl_xor(a, m, 64);
    if (lane == 0) aw[s] = a + hp;
  }
  __syncthreads();
  // softmax over aw[0..127]
  float sc = (t < S) ? aw[t] : -INFINITY;
  red[t] = sc; __syncthreads();
  for (int off = 128; off; off >>= 1) {
    if (t < off) red[t] = fmaxf(red[t], red[t + off]);
    __syncthreads();
  }
  float mx = red[0]; __syncthreads();
  float e = (t < S) ? __expf(sc - mx) : 0.f;
  red[t] = e; __syncthreads();
  for (int off = 128; off; off >>= 1) {
    if (t < off) red[t] += red[t + off];
    __syncthreads();
  }
  float inv = 1.f / red[0];
  if (t < S) {
    float w = e * inv;
    aw[t] = w;
    attn_out[(long long)b * S + t] = w;
  }
  __syncthreads();
  // context (full s-sum, no partials) + xcat assembly
  const float4* e4 = (const float4*)(enc + (long long)b * S * H);
  float4 a0 = {0.f,0.f,0.f,0.f}, a1 = {0.f,0.f,0.f,0.f};
#pragma unroll 4
  for (int s = 0; s < S; s += 2) {
    float4 v0 = e4[(long long)s * (H / 4) + t];
    float4 v1 = e4[(long long)(s + 1) * (H / 4) + t];
    float c0 = aw[s], c1 = aw[s + 1];
    a0.x += c0 * v0.x; a0.y += c0 * v0.y; a0.z += c0 * v0.z; a0.w += c0 * v0.w;
    a1.x += c1 * v1.x; a1.y += c1 * v1.y; a1.z += c1 * v1.z; a1.w += c1 * v1.w;
  }
  a0.x += a1.x; a0.y += a1.y; a0.z += a1.z; a0.w += a1.w;
  float4* x4 = (float4*)xcat;
  x4[b * 512 + 256 + t] = a0;                                    // context half
  x4[b * 512 + t] = ((const float4*)emb)[(long long)idx[b] * 256 + t];  // emb half
}

// ---------------- K6: sum split-K partials, LSTM cell, mask -----------------
__global__ __launch_bounds__(256) void k_lstm(
    const float* __restrict__ part, const float* __restrict__ b_ih,
    const float* __restrict__ b_hh, const float* __restrict__ c0,
    const int* __restrict__ lengths,
    float* __restrict__ h1, float* __restrict__ c1) {
  int ft = blockIdx.x * 256 + threadIdx.x;   // [0, B*H)
  int b = ft >> 10, h = ft & 1023;
  float gs[4] = {0.f, 0.f, 0.f, 0.f};
  for (int ks = 0; ks < 6; ++ks) {
    const float* p = part + (long long)(ks * B + b) * 4096;
#pragma unroll
    for (int q = 0; q < 4; ++q) gs[q] += p[q * H + h];
  }
#pragma unroll
  for (int q = 0; q < 4; ++q) gs[q] += b_ih[q * H + h] + b_hh[q * H + h];
  float ig = 1.f / (1.f + expf(-gs[0]));
  float fg = 1.f / (1.f + expf(-gs[1]));
  float gg = tanhf(gs[2]);
  float og = 1.f / (1.f + expf(-gs[3]));
  float c = fg * c0[ft] + ig * gg;
  float hh = og * tanhf(c);
  if (lengths[b] == 0) { c = 0.f; hh = 0.f; }
  h1[ft] = hh; c1[ft] = c;
}

// ---- Cooperative logits: GEMM+partials -> grid.sync -> lc -> grid.sync ----
// -> in-place logprob finish (L2-hot). Replaces k_logits + k_lsm_comb +
// k_lsm_fin. 500 blocks; __launch_bounds__(256,2) guarantees 2 blocks/CU
// (>= 500 co-resident across 256 CUs) for the cooperative launch.
__global__ __launch_bounds__(256, 2) void k_logits_coop(
    const float* __restrict__ W_out, const float* __restrict__ h1,
    float* __restrict__ logits, const float* __restrict__ b_out,
    float* __restrict__ pm, float* __restrict__ pl, float* __restrict__ lc) {
  cg::grid_group grid = cg::this_grid();
  gemm_body(W_out, H, h1, H, blockIdx.x * 64, 0, H, logits, V, b_out, pm, pl);
  grid.sync();
  if (blockIdx.x < B) {
    // combine 500 per-block partials for row b -> lc[b] = M + log(L)
    __shared__ float red[256];
    int b = blockIdx.x, t = threadIdx.x;
    float v0 = pm[b * 512 + t];                       // t < 256 < 500: valid
    float v1 = (t + 256 < 500) ? pm[b * 512 + t + 256] : -INFINITY;
    red[t] = fmaxf(v0, v1); __syncthreads();
    for (int off = 128; off; off >>= 1) {
      if (t < off) red[t] = fmaxf(red[t], red[t + off]);
      __syncthreads();
    }
    float M = red[0]; __syncthreads();
    float s2 = pl[b * 512 + t] * __expf(v0 - M);
    if (t + 256 < 500) s2 += pl[b * 512 + t + 256] * __expf(v1 - M);
    red[t] = s2; __syncthreads();
    for (int off = 128; off; off >>= 1) {
      if (t < off) red[t] += red[t + off];
      __syncthreads();
    }
    if (t == 0) lc[b] = M + logf(red[0]);
  }
  grid.sync();
  // logprobs = logits - lc[b], in place (tile just written -> L2-hot)
  float4* p4 = (float4*)logits;
  const int nf4 = B * V / 4;                          // 512000
  for (int fi = blockIdx.x * 256 + threadIdx.x; fi < nf4; fi += 500 * 256) {
    float4 x = p4[fi];
    float c = lc[fi / 8000];                          // 8000 float4 per row
    x.x -= c; x.y -= c; x.z -= c; x.w -= c;
    p4[fi] = x;
  }
}

extern "C" void kernel_launch(void* const* d_in, const int* in_sizes, int n_in,
                              void* d_out, int out_size, void* d_ws, size_t ws_size,
                              hipStream_t stream) {
  const int*   input_batch = (const int*)d_in[0];
  const float* prev_h = (const float*)d_in[1];
  const float* prev_c = (const float*)d_in[2];
  const float* enc    = (const float*)d_in[3];
  const int*   lengths= (const int*)d_in[4];
  const float* emb    = (const float*)d_in[5];
  const float* attn_w = (const float*)d_in[6];
  const float* attn_b = (const float*)d_in[7];
  const float* W_ih   = (const float*)d_in[8];
  const float* W_hh   = (const float*)d_in[9];
  const float* b_ih   = (const float*)d_in[10];
  const float* b_hh   = (const float*)d_in[11];
  const float* W_out  = (const float*)d_in[12];
  const float* b_out  = (const float*)d_in[13];

  float* out = (float*)d_out;
  float* ws  = (float*)d_ws;

  float* xcat   = ws + WS_XCAT;
  float* part   = ws + WS_PART;
  float* pm     = ws + WS_PM;
  float* pl     = ws + WS_PL;
  float* lc     = ws + WS_LC;

  float* logits = out;             // logprobs region, used as logits scratch
  float* h1     = out + OUT_H1;
  float* c1     = out + OUT_C1;
  float* attn   = out + OUT_ATTN;

  // fused attention: scores + softmax + context + xcat (enc read once)
  k_attn<<<dim3(B), 256, 0, stream>>>(enc, prev_h, attn_w, attn_b,
                                      emb, input_batch, attn, xcat);

  // gates = xcat @ W_ih^T (split-K 4) + h0 @ W_hh^T (split-K 2) -> 6 partials
  k_gates_mfma<<<dim3(64, 6), 256, 0, stream>>>(W_ih, xcat, W_hh, prev_h, part);
  k_lstm<<<dim3(B * H / 256), 256, 0, stream>>>(part, b_ih, b_hh, prev_c,
                                                lengths, h1, c1);

  // logits GEMM + fused log-softmax (cooperative, grid-wide sync)
  void* args[] = {(void*)&W_out, (void*)&h1, (void*)&logits, (void*)&b_out,
                  (void*)&pm, (void*)&pl, (void*)&lc};
  hipLaunchCooperativeKernel((const void*)k_logits_coop, dim3(V / 64),
                             dim3(256), args, 0, stream);
}

// Round 4
// 367.302 us; speedup vs baseline: 1.3929x; 1.3929x over previous
//
#include <hip/hip_runtime.h>
#include <math.h>

constexpr int V = 32000, H = 1024, E = 1024, B = 64, S = 128;
constexpr int KX = 2048;                      // xcat = [emb | context]

// d_out offsets (floats), return order: logprobs, h1, c1, attn_weights
constexpr long long OUT_H1   = (long long)B * V;      // 2048000
constexpr long long OUT_C1   = OUT_H1 + (long long)B * H;
constexpr long long OUT_ATTN = OUT_C1 + (long long)B * H;

// ws offsets (floats) — scores/ctxp regions retired (fused attn), layout kept
constexpr long long WS_SCORES = 0;                                  // unused
constexpr long long WS_XCAT   = WS_SCORES + (long long)B * S;       // B*2048
constexpr long long WS_PART   = WS_XCAT + (long long)B * KX;        // 6*B*4096
constexpr long long WS_CTXP   = WS_PART + 6LL * B * 4096;           // unused
constexpr long long WS_PM     = WS_CTXP + 4LL * B * H;              // 64*512
constexpr long long WS_PL     = WS_PM + 64 * 512;                   // 64*512
constexpr long long WS_LC     = WS_PL + 64 * 512;                   // 64

typedef __attribute__((ext_vector_type(8))) short short8;
typedef __attribute__((ext_vector_type(4))) float f32x4;

__device__ __forceinline__ unsigned short f2bf(float f) {
  unsigned u = __float_as_uint(f);
  u += 0x7FFF + ((u >> 16) & 1);          // round-to-nearest-even
  return (unsigned short)(u >> 16);
}

__device__ __forceinline__ short8 pack8(float4 a, float4 b) {
  short8 s;
  s[0] = (short)f2bf(a.x); s[1] = (short)f2bf(a.y);
  s[2] = (short)f2bf(a.z); s[3] = (short)f2bf(a.w);
  s[4] = (short)f2bf(b.x); s[5] = (short)f2bf(b.y);
  s[6] = (short)f2bf(b.z); s[7] = (short)f2bf(b.w);
  return s;
}

// ---- MFMA GEMM body: dst[b, g0+g] (+bias) = sum_k W[g0+g, k0+k] X[b, k0+k] -
// 64(g) x 64(b) tile per block, bf16 16x16x32 MFMA, fp32->bf16 in registers.
// Software-pipelined: K-tile kt+1 global loads issued before MFMA phase of kt.
// LDS: bf16 tiles, row stride 64, 8-bf16 chunks XOR-swizzled by (row&7).
// If pm != nullptr: also emit per-block log-softmax partials over the 64
// g-rows (pm[b*512+blk] = max, pl[b*512+blk] = sum exp(v - max)).
__device__ __forceinline__ void gemm_body(
    const float* __restrict__ W, int ldw,
    const float* __restrict__ X, int ldx,
    int g0, int k0, int KC,
    float* __restrict__ dst, int ldo, const float* __restrict__ bias,
    float* __restrict__ pm, float* __restrict__ pl) {
  __shared__ __align__(16) unsigned short Wl[64 * 64];
  __shared__ __align__(16) unsigned short Xl[64 * 64];
  __shared__ float pmx[4][64];
  __shared__ float psm[4][64];
  int t = threadIdx.x;
  int lane = t & 63, wid = t >> 6;
  int n = lane & 15, quad = lane >> 4;
  // staging: 512 chunks (8 bf16) per tile, 2 per thread
  int r0 = t >> 3,          c0 = t & 7;
  int r1 = (t + 256) >> 3,  c1 = (t + 256) & 7;
  int ws0 = r0 * 64 + (c0 ^ (r0 & 7)) * 8;
  int ws1 = r1 * 64 + (c1 ^ (r1 & 7)) * 8;
  f32x4 acc[4] = {{0.f,0.f,0.f,0.f},{0.f,0.f,0.f,0.f},
                  {0.f,0.f,0.f,0.f},{0.f,0.f,0.f,0.f}};
  const float* wp0 = W + (long long)(g0 + r0) * ldw + k0 + c0 * 8;
  const float* wp1 = W + (long long)(g0 + r1) * ldw + k0 + c1 * 8;
  const float* xp0 = X + (long long)r0 * ldx + k0 + c0 * 8;
  const float* xp1 = X + (long long)r1 * ldx + k0 + c1 * 8;
  // prefetch K-tile 0
  float4 wa = ((const float4*)wp0)[0], wb = ((const float4*)wp0)[1];
  float4 wc = ((const float4*)wp1)[0], wd = ((const float4*)wp1)[1];
  float4 xa = ((const float4*)xp0)[0], xb = ((const float4*)xp0)[1];
  float4 xc = ((const float4*)xp1)[0], xd = ((const float4*)xp1)[1];

  for (int kt = 0; kt < KC; kt += 64) {
    __syncthreads();                       // prior compute's LDS reads done
    *(short8*)&Wl[ws0] = pack8(wa, wb);
    *(short8*)&Wl[ws1] = pack8(wc, wd);
    *(short8*)&Xl[ws0] = pack8(xa, xb);
    *(short8*)&Xl[ws1] = pack8(xc, xd);
    __syncthreads();
    if (kt + 64 < KC) {                    // issue next tile's loads now;
      int o = kt + 64;                     // consumed at next LDS write
      wa = *(const float4*)(wp0 + o); wb = *(const float4*)(wp0 + o + 4);
      wc = *(const float4*)(wp1 + o); wd = *(const float4*)(wp1 + o + 4);
      xa = *(const float4*)(xp0 + o); xb = *(const float4*)(xp0 + o + 4);
      xc = *(const float4*)(xp1 + o); xd = *(const float4*)(xp1 + o + 4);
    }
#pragma unroll
    for (int kc = 0; kc < 2; ++kc) {
      short8 af = *(const short8*)&Wl[(wid * 16 + n) * 64 +
                                      (((kc * 4 + quad) ^ (n & 7)) * 8)];
#pragma unroll
      for (int nt = 0; nt < 4; ++nt) {
        short8 bf = *(const short8*)&Xl[(nt * 16 + n) * 64 +
                                        (((kc * 4 + quad) ^ (n & 7)) * 8)];
        acc[nt] = __builtin_amdgcn_mfma_f32_16x16x32_bf16(af, bf, acc[nt], 0, 0, 0);
      }
    }
  }
  // epilogue: C/D layout col=lane&15 (b), row=quad*4+reg (g-local)
  int gl = wid * 16 + quad * 4;
  float bs[4] = {0.f, 0.f, 0.f, 0.f};
  if (bias) {
#pragma unroll
    for (int r = 0; r < 4; ++r) bs[r] = bias[g0 + gl + r];
  }
  float v[4][4];
#pragma unroll
  for (int nt = 0; nt < 4; ++nt) {
    int b = nt * 16 + n;
#pragma unroll
    for (int r = 0; r < 4; ++r) {
      v[nt][r] = acc[nt][r] + bs[r];
      dst[(long long)b * ldo + g0 + gl + r] = v[nt][r];
    }
  }
  if (pm) {
    // per-block log-softmax partials over this block's 64 rows, per b
    float tmax[4];
#pragma unroll
    for (int nt = 0; nt < 4; ++nt) {
      tmax[nt] = fmaxf(fmaxf(v[nt][0], v[nt][1]), fmaxf(v[nt][2], v[nt][3]));
      tmax[nt] = fmaxf(tmax[nt], __shfl_xor(tmax[nt], 16, 64));
      tmax[nt] = fmaxf(tmax[nt], __shfl_xor(tmax[nt], 32, 64));
    }
    if (lane < 16) {
#pragma unroll
      for (int nt = 0; nt < 4; ++nt) pmx[wid][nt * 16 + lane] = tmax[nt];
    }
    __syncthreads();
    float bmax[4], tsum[4];
#pragma unroll
    for (int nt = 0; nt < 4; ++nt) {
      bmax[nt] = fmaxf(fmaxf(pmx[0][nt * 16 + n], pmx[1][nt * 16 + n]),
                       fmaxf(pmx[2][nt * 16 + n], pmx[3][nt * 16 + n]));
      tsum[nt] = __expf(v[nt][0] - bmax[nt]) + __expf(v[nt][1] - bmax[nt]) +
                 __expf(v[nt][2] - bmax[nt]) + __expf(v[nt][3] - bmax[nt]);
      tsum[nt] += __shfl_xor(tsum[nt], 16, 64);
      tsum[nt] += __shfl_xor(tsum[nt], 32, 64);
    }
    if (lane < 16) {
#pragma unroll
      for (int nt = 0; nt < 4; ++nt) psm[wid][nt * 16 + lane] = tsum[nt];
    }
    __syncthreads();
    if (t < 64) {
      float M = fmaxf(fmaxf(pmx[0][t], pmx[1][t]), fmaxf(pmx[2][t], pmx[3][t]));
      float L = psm[0][t] + psm[1][t] + psm[2][t] + psm[3][t];
      pm[t * 512 + blockIdx.x] = M;
      pl[t * 512 + blockIdx.x] = L;
    }
  }
}

// gates: grid (64, 6). y<4: W_ih K-split 4; y>=4: W_hh K-split 2.
__global__ __launch_bounds__(256) void k_gates_mfma(
    const float* __restrict__ W_ih, const float* __restrict__ xcat,
    const float* __restrict__ W_hh, const float* __restrict__ h0,
    float* __restrict__ part) {
  int y = blockIdx.y;
  if (y < 4)
    gemm_body(W_ih, KX, xcat, KX, blockIdx.x * 64, y * 512, 512,
              part + (long long)y * B * 4096, 4096, nullptr, nullptr, nullptr);
  else
    gemm_body(W_hh, H, h0, H, blockIdx.x * 64, (y - 4) * 512, 512,
              part + (long long)y * B * 4096, 4096, nullptr, nullptr, nullptr);
}

// logits: grid (500). dst = logits [b][V], bias = b_out, + lsm partials.
__global__ __launch_bounds__(256) void k_logits_mfma(
    const float* __restrict__ W_out, const float* __restrict__ h1,
    float* __restrict__ logits, const float* __restrict__ b_out,
    float* __restrict__ pm, float* __restrict__ pl) {
  gemm_body(W_out, H, h1, H, blockIdx.x * 64, 0, H, logits, V, b_out, pm, pl);
}

// ---- K_ATTN: fused scores + softmax + context + xcat. One block per b. -----
// Harness-verified in round 1 (256 threads). enc[b] slice (512 KB) is read
// twice per block: once from HBM (scores), once L2-hot (context).
// Replaces 4 kernels (scores/softmax/ctx/xcat).
__global__ __launch_bounds__(256) void k_attn(
    const float* __restrict__ enc, const float* __restrict__ h0,
    const float* __restrict__ attn_w, const float* __restrict__ attn_b,
    const float* __restrict__ emb, const int* __restrict__ idx,
    float* __restrict__ attn_out, float* __restrict__ xcat) {
  __shared__ float red[256];
  __shared__ float aw[S];                        // raw scores, then weights
  int b = blockIdx.x, t = threadIdx.x;
  int lane = t & 63, wv = t >> 6;
  // h_part = dot(h0[b], attn_w[:H]) + attn_b
  const float4* h4  = (const float4*)(h0 + (long long)b * H);
  const float4* w4l = (const float4*)attn_w;
  float4 hv = h4[t], wvv = w4l[t];
  float p = hv.x * wvv.x + hv.y * wvv.y + hv.z * wvv.z + hv.w * wvv.w;
#pragma unroll
  for (int m = 32; m; m >>= 1) p += __shfl_xor(p, m, 64);
  if (lane == 0) red[wv] = p;
  __syncthreads();
  float hp = red[0] + red[1] + red[2] + red[3] + attn_b[0];
  // attn_w[H:] resident in registers for the scores loop
  const float4* w4h = (const float4*)(attn_w + H);
  float4 wreg[4];
#pragma unroll
  for (int j = 0; j < 4; ++j) wreg[j] = w4h[lane + 64 * j];
  __syncthreads();                               // red[0..3] consumed
  // scores: wave wv owns s = wv*32 + i (coalesced 1 KB row segments)
  for (int i = 0; i < 32; ++i) {
    int s = wv * 32 + i;
    const float4* e4 = (const float4*)(enc + (long long)(b * S + s) * H);
    float a = 0.f;
#pragma unroll
    for (int j = 0; j < 4; ++j) {
      float4 e = e4[lane + 64 * j];
      a += e.x * wreg[j].x + e.y * wreg[j].y + e.z * wreg[j].z + e.w * wreg[j].w;
    }
#pragma unroll
    for (int m = 32; m; m >>= 1) a += __shfl_xor(a, m, 64);
    if (lane == 0) aw[s] = a + hp;
  }
  __syncthreads();
  // softmax over aw[0..127]
  float sc = (t < S) ? aw[t] : -INFINITY;
  red[t] = sc; __syncthreads();
  for (int off = 128; off; off >>= 1) {
    if (t < off) red[t] = fmaxf(red[t], red[t + off]);
    __syncthreads();
  }
  float mx = red[0]; __syncthreads();
  float e = (t < S) ? __expf(sc - mx) : 0.f;
  red[t] = e; __syncthreads();
  for (int off = 128; off; off >>= 1) {
    if (t < off) red[t] += red[t + off];
    __syncthreads();
  }
  float inv = 1.f / red[0];
  if (t < S) {
    float w = e * inv;
    aw[t] = w;
    attn_out[(long long)b * S + t] = w;
  }
  __syncthreads();
  // context (full s-sum, no partials) + xcat assembly
  const float4* e4 = (const float4*)(enc + (long long)b * S * H);
  float4 a0 = {0.f,0.f,0.f,0.f}, a1 = {0.f,0.f,0.f,0.f};
#pragma unroll 4
  for (int s = 0; s < S; s += 2) {
    float4 v0 = e4[(long long)s * (H / 4) + t];
    float4 v1 = e4[(long long)(s + 1) * (H / 4) + t];
    float c0 = aw[s], c1 = aw[s + 1];
    a0.x += c0 * v0.x; a0.y += c0 * v0.y; a0.z += c0 * v0.z; a0.w += c0 * v0.w;
    a1.x += c1 * v1.x; a1.y += c1 * v1.y; a1.z += c1 * v1.z; a1.w += c1 * v1.w;
  }
  a0.x += a1.x; a0.y += a1.y; a0.z += a1.z; a0.w += a1.w;
  float4* x4 = (float4*)xcat;
  x4[b * 512 + 256 + t] = a0;                                    // context half
  x4[b * 512 + t] = ((const float4*)emb)[(long long)idx[b] * 256 + t];  // emb half
}

// ---------------- K6: sum split-K partials, LSTM cell, mask -----------------
__global__ __launch_bounds__(256) void k_lstm(
    const float* __restrict__ part, const float* __restrict__ b_ih,
    const float* __restrict__ b_hh, const float* __restrict__ c0,
    const int* __restrict__ lengths,
    float* __restrict__ h1, float* __restrict__ c1) {
  int ft = blockIdx.x * 256 + threadIdx.x;   // [0, B*H)
  int b = ft >> 10, h = ft & 1023;
  float gs[4] = {0.f, 0.f, 0.f, 0.f};
  for (int ks = 0; ks < 6; ++ks) {
    const float* p = part + (long long)(ks * B + b) * 4096;
#pragma unroll
    for (int q = 0; q < 4; ++q) gs[q] += p[q * H + h];
  }
#pragma unroll
  for (int q = 0; q < 4; ++q) gs[q] += b_ih[q * H + h] + b_hh[q * H + h];
  float ig = 1.f / (1.f + expf(-gs[0]));
  float fg = 1.f / (1.f + expf(-gs[1]));
  float gg = tanhf(gs[2]);
  float og = 1.f / (1.f + expf(-gs[3]));
  float c = fg * c0[ft] + ig * gg;
  float hh = og * tanhf(c);
  if (lengths[b] == 0) { c = 0.f; hh = 0.f; }
  h1[ft] = hh; c1[ft] = c;
}

// ------ K9: combine 500 per-block partials per row -> lc[b] = M + log(L) ----
__global__ __launch_bounds__(256) void k_lsm_comb(
    const float* __restrict__ pm, const float* __restrict__ pl,
    float* __restrict__ lc) {
  __shared__ float red[256];
  int b = blockIdx.x, t = threadIdx.x;
  float v0 = pm[b * 512 + t];                       // t < 256 < 500: valid
  float v1 = (t + 256 < 500) ? pm[b * 512 + t + 256] : -INFINITY;
  red[t] = fmaxf(v0, v1); __syncthreads();
  for (int off = 128; off; off >>= 1) {
    if (t < off) red[t] = fmaxf(red[t], red[t + off]);
    __syncthreads();
  }
  float M = red[0]; __syncthreads();
  float s = pl[b * 512 + t] * __expf(v0 - M);
  if (t + 256 < 500) s += pl[b * 512 + t + 256] * __expf(v1 - M);
  red[t] = s; __syncthreads();
  for (int off = 128; off; off >>= 1) {
    if (t < off) red[t] += red[t + off];
    __syncthreads();
  }
  if (t == 0) lc[b] = M + logf(red[0]);
}

// ---------------- K10: logprobs = logits - lc[b], in place ------------------
__global__ __launch_bounds__(256) void k_lsm_fin(
    float* __restrict__ logits, const float* __restrict__ lc) {
  int fi = blockIdx.x * 256 + threadIdx.x;   // float4 index, < 512000
  float4* p = (float4*)logits;
  float4 x = p[fi];
  float c = lc[fi / 8000];                   // 8000 float4 per row
  x.x -= c; x.y -= c; x.z -= c; x.w -= c;
  p[fi] = x;
}

extern "C" void kernel_launch(void* const* d_in, const int* in_sizes, int n_in,
                              void* d_out, int out_size, void* d_ws, size_t ws_size,
                              hipStream_t stream) {
  const int*   input_batch = (const int*)d_in[0];
  const float* prev_h = (const float*)d_in[1];
  const float* prev_c = (const float*)d_in[2];
  const float* enc    = (const float*)d_in[3];
  const int*   lengths= (const int*)d_in[4];
  const float* emb    = (const float*)d_in[5];
  const float* attn_w = (const float*)d_in[6];
  const float* attn_b = (const float*)d_in[7];
  const float* W_ih   = (const float*)d_in[8];
  const float* W_hh   = (const float*)d_in[9];
  const float* b_ih   = (const float*)d_in[10];
  const float* b_hh   = (const float*)d_in[11];
  const float* W_out  = (const float*)d_in[12];
  const float* b_out  = (const float*)d_in[13];

  float* out = (float*)d_out;
  float* ws  = (float*)d_ws;

  float* xcat   = ws + WS_XCAT;
  float* part   = ws + WS_PART;
  float* pm     = ws + WS_PM;
  float* pl     = ws + WS_PL;
  float* lc     = ws + WS_LC;

  float* logits = out;             // logprobs region, used as logits scratch
  float* h1     = out + OUT_H1;
  float* c1     = out + OUT_C1;
  float* attn   = out + OUT_ATTN;

  // fused attention: scores + softmax + context + xcat (enc read once/HBM)
  k_attn<<<dim3(B), 256, 0, stream>>>(enc, prev_h, attn_w, attn_b,
                                      emb, input_batch, attn, xcat);

  // gates = xcat @ W_ih^T (split-K 4) + h0 @ W_hh^T (split-K 2) -> 6 partials
  k_gates_mfma<<<dim3(64, 6), 256, 0, stream>>>(W_ih, xcat, W_hh, prev_h, part);
  k_lstm<<<dim3(B * H / 256), 256, 0, stream>>>(part, b_ih, b_hh, prev_c,
                                                lengths, h1, c1);

  // logits = h1 @ W_out^T + b_out, fused log-softmax partials
  k_logits_mfma<<<dim3(V / 64), 256, 0, stream>>>(W_out, h1, logits, b_out, pm, pl);

  // log-softmax over V, in place
  k_lsm_comb<<<dim3(B), 256, 0, stream>>>(pm, pl, lc);
  k_lsm_fin <<<dim3(B * V / 4 / 256), 256, 0, stream>>>(logits, lc);
}

// Round 6
// 348.385 us; speedup vs baseline: 1.4686x; 1.0543x over previous
//
#include <hip/hip_runtime.h>
#include <math.h>

constexpr int V = 32000, H = 1024, E = 1024, B = 64, S = 128;
constexpr int KX = 2048;                      // xcat = [emb | context]

// d_out offsets (floats), return order: logprobs, h1, c1, attn_weights
constexpr long long OUT_H1   = (long long)B * V;      // 2048000
constexpr long long OUT_C1   = OUT_H1 + (long long)B * H;
constexpr long long OUT_ATTN = OUT_C1 + (long long)B * H;

// ws offsets (floats)
constexpr long long WS_SCORES = 0;                                  // B*S
constexpr long long WS_XCAT   = WS_SCORES + (long long)B * S;       // B*2048
constexpr long long WS_PART   = WS_XCAT + (long long)B * KX;        // 6*B*4096
constexpr long long WS_CTXP   = WS_PART + 6LL * B * 4096;           // 8*B*H
constexpr long long WS_PM     = WS_CTXP + 8LL * B * H;              // 64*512
constexpr long long WS_PL     = WS_PM + 64 * 512;                   // 64*512
constexpr long long WS_LC     = WS_PL + 64 * 512;                   // 64

typedef __attribute__((ext_vector_type(8))) short short8;
typedef __attribute__((ext_vector_type(4))) float f32x4;

__device__ __forceinline__ unsigned short f2bf(float f) {
  unsigned u = __float_as_uint(f);
  u += 0x7FFF + ((u >> 16) & 1);          // round-to-nearest-even
  return (unsigned short)(u >> 16);
}

__device__ __forceinline__ short8 pack8(float4 a, float4 b) {
  short8 s;
  s[0] = (short)f2bf(a.x); s[1] = (short)f2bf(a.y);
  s[2] = (short)f2bf(a.z); s[3] = (short)f2bf(a.w);
  s[4] = (short)f2bf(b.x); s[5] = (short)f2bf(b.y);
  s[6] = (short)f2bf(b.z); s[7] = (short)f2bf(b.w);
  return s;
}

// ---- MFMA GEMM body: dst[b, g0+g] (+bias) = sum_k W[g0+g, k0+k] X[b, k0+k] -
// 64(g) x 64(b) tile per block, bf16 16x16x32 MFMA, fp32->bf16 in registers.
// Software-pipelined: K-tile kt+1 global loads issued before MFMA phase of kt.
// LDS: bf16 tiles, row stride 64, 8-bf16 chunks XOR-swizzled by (row&7).
// If pm != nullptr: also emit per-block log-softmax partials over the 64
// g-rows (pm[b*512+blk] = max, pl[b*512+blk] = sum exp(v - max)).
__device__ __forceinline__ void gemm_body(
    const float* __restrict__ W, int ldw,
    const float* __restrict__ X, int ldx,
    int g0, int k0, int KC,
    float* __restrict__ dst, int ldo, const float* __restrict__ bias,
    float* __restrict__ pm, float* __restrict__ pl) {
  __shared__ __align__(16) unsigned short Wl[64 * 64];
  __shared__ __align__(16) unsigned short Xl[64 * 64];
  __shared__ float pmx[4][64];
  __shared__ float psm[4][64];
  int t = threadIdx.x;
  int lane = t & 63, wid = t >> 6;
  int n = lane & 15, quad = lane >> 4;
  // staging: 512 chunks (8 bf16) per tile, 2 per thread
  int r0 = t >> 3,          c0 = t & 7;
  int r1 = (t + 256) >> 3,  c1 = (t + 256) & 7;
  int ws0 = r0 * 64 + (c0 ^ (r0 & 7)) * 8;
  int ws1 = r1 * 64 + (c1 ^ (r1 & 7)) * 8;
  f32x4 acc[4] = {{0.f,0.f,0.f,0.f},{0.f,0.f,0.f,0.f},
                  {0.f,0.f,0.f,0.f},{0.f,0.f,0.f,0.f}};
  const float* wp0 = W + (long long)(g0 + r0) * ldw + k0 + c0 * 8;
  const float* wp1 = W + (long long)(g0 + r1) * ldw + k0 + c1 * 8;
  const float* xp0 = X + (long long)r0 * ldx + k0 + c0 * 8;
  const float* xp1 = X + (long long)r1 * ldx + k0 + c1 * 8;
  // prefetch K-tile 0
  float4 wa = ((const float4*)wp0)[0], wb = ((const float4*)wp0)[1];
  float4 wc = ((const float4*)wp1)[0], wd = ((const float4*)wp1)[1];
  float4 xa = ((const float4*)xp0)[0], xb = ((const float4*)xp0)[1];
  float4 xc = ((const float4*)xp1)[0], xd = ((const float4*)xp1)[1];

  for (int kt = 0; kt < KC; kt += 64) {
    __syncthreads();                       // prior compute's LDS reads done
    *(short8*)&Wl[ws0] = pack8(wa, wb);
    *(short8*)&Wl[ws1] = pack8(wc, wd);
    *(short8*)&Xl[ws0] = pack8(xa, xb);
    *(short8*)&Xl[ws1] = pack8(xc, xd);
    __syncthreads();
    if (kt + 64 < KC) {                    // issue next tile's loads now;
      int o = kt + 64;                     // consumed at next LDS write
      wa = *(const float4*)(wp0 + o); wb = *(const float4*)(wp0 + o + 4);
      wc = *(const float4*)(wp1 + o); wd = *(const float4*)(wp1 + o + 4);
      xa = *(const float4*)(xp0 + o); xb = *(const float4*)(xp0 + o + 4);
      xc = *(const float4*)(xp1 + o); xd = *(const float4*)(xp1 + o + 4);
    }
#pragma unroll
    for (int kc = 0; kc < 2; ++kc) {
      short8 af = *(const short8*)&Wl[(wid * 16 + n) * 64 +
                                      (((kc * 4 + quad) ^ (n & 7)) * 8)];
#pragma unroll
      for (int nt = 0; nt < 4; ++nt) {
        short8 bf = *(const short8*)&Xl[(nt * 16 + n) * 64 +
                                        (((kc * 4 + quad) ^ (n & 7)) * 8)];
        acc[nt] = __builtin_amdgcn_mfma_f32_16x16x32_bf16(af, bf, acc[nt], 0, 0, 0);
      }
    }
  }
  // epilogue: C/D layout col=lane&15 (b), row=quad*4+reg (g-local)
  int gl = wid * 16 + quad * 4;
  float bs[4] = {0.f, 0.f, 0.f, 0.f};
  if (bias) {
#pragma unroll
    for (int r = 0; r < 4; ++r) bs[r] = bias[g0 + gl + r];
  }
  float v[4][4];
#pragma unroll
  for (int nt = 0; nt < 4; ++nt) {
    int b = nt * 16 + n;
#pragma unroll
    for (int r = 0; r < 4; ++r) {
      v[nt][r] = acc[nt][r] + bs[r];
      dst[(long long)b * ldo + g0 + gl + r] = v[nt][r];
    }
  }
  if (pm) {
    // per-block log-softmax partials over this block's 64 rows, per b
    float tmax[4];
#pragma unroll
    for (int nt = 0; nt < 4; ++nt) {
      tmax[nt] = fmaxf(fmaxf(v[nt][0], v[nt][1]), fmaxf(v[nt][2], v[nt][3]));
      tmax[nt] = fmaxf(tmax[nt], __shfl_xor(tmax[nt], 16, 64));
      tmax[nt] = fmaxf(tmax[nt], __shfl_xor(tmax[nt], 32, 64));
    }
    if (lane < 16) {
#pragma unroll
      for (int nt = 0; nt < 4; ++nt) pmx[wid][nt * 16 + lane] = tmax[nt];
    }
    __syncthreads();
    float bmax[4], tsum[4];
#pragma unroll
    for (int nt = 0; nt < 4; ++nt) {
      bmax[nt] = fmaxf(fmaxf(pmx[0][nt * 16 + n], pmx[1][nt * 16 + n]),
                       fmaxf(pmx[2][nt * 16 + n], pmx[3][nt * 16 + n]));
      tsum[nt] = __expf(v[nt][0] - bmax[nt]) + __expf(v[nt][1] - bmax[nt]) +
                 __expf(v[nt][2] - bmax[nt]) + __expf(v[nt][3] - bmax[nt]);
      tsum[nt] += __shfl_xor(tsum[nt], 16, 64);
      tsum[nt] += __shfl_xor(tsum[nt], 32, 64);
    }
    if (lane < 16) {
#pragma unroll
      for (int nt = 0; nt < 4; ++nt) psm[wid][nt * 16 + lane] = tsum[nt];
    }
    __syncthreads();
    if (t < 64) {
      float M = fmaxf(fmaxf(pmx[0][t], pmx[1][t]), fmaxf(pmx[2][t], pmx[3][t]));
      float L = psm[0][t] + psm[1][t] + psm[2][t] + psm[3][t];
      pm[t * 512 + blockIdx.x] = M;
      pl[t * 512 + blockIdx.x] = L;
    }
  }
}

// gates: grid (64, 6). y<4: W_ih K-split 4; y>=4: W_hh K-split 2.
__global__ __launch_bounds__(256) void k_gates_mfma(
    const float* __restrict__ W_ih, const float* __restrict__ xcat,
    const float* __restrict__ W_hh, const float* __restrict__ h0,
    float* __restrict__ part) {
  int y = blockIdx.y;
  if (y < 4)
    gemm_body(W_ih, KX, xcat, KX, blockIdx.x * 64, y * 512, 512,
              part + (long long)y * B * 4096, 4096, nullptr, nullptr, nullptr);
  else
    gemm_body(W_hh, H, h0, H, blockIdx.x * 64, (y - 4) * 512, 512,
              part + (long long)y * B * 4096, 4096, nullptr, nullptr, nullptr);
}

// logits: grid (500). dst = logits [b][V], bias = b_out, + lsm partials.
__global__ __launch_bounds__(256) void k_logits_mfma(
    const float* __restrict__ W_out, const float* __restrict__ h1,
    float* __restrict__ logits, const float* __restrict__ b_out,
    float* __restrict__ pm, float* __restrict__ pl) {
  gemm_body(W_out, H, h1, H, blockIdx.x * 64, 0, H, logits, V, b_out, pm, pl);
}

// ---------------- K1: e_part[b,s] = dot(enc[b,s,:], attn_w[H:]) -------------
// 2048 blocks x 4 waves: one wave per (b,s) row — full-GPU enc pass at BW.
__global__ __launch_bounds__(256) void k_scores(
    const float* __restrict__ enc, const float* __restrict__ attn_w,
    float* __restrict__ scores) {
  int w = (blockIdx.x * 256 + threadIdx.x) >> 6;   // (b*S+s) in [0, 8192)
  int lane = threadIdx.x & 63;
  const float4* e4 = (const float4*)(enc + (long long)w * H);
  const float4* w4 = (const float4*)(attn_w + H);
  float acc = 0.f;
#pragma unroll
  for (int i = 0; i < 4; ++i) {
    float4 a = e4[lane + 64 * i];
    float4 b = w4[lane + 64 * i];
    acc += a.x * b.x + a.y * b.y + a.z * b.z + a.w * b.w;
  }
#pragma unroll
  for (int m = 32; m; m >>= 1) acc += __shfl_xor(acc, m, 64);
  if (lane == 0) scores[w] = acc;
}

// ---- K2: redundant softmax + context partial. grid (B, 8), 256 threads. ----
// Each block: h_part dot (redundant), softmax over the 128 scores
// (redundant, cheap), then context partial over its 16 s-rows (enc
// L2/L3-hot after k_scores). sq==0 also writes attn_out + emb half of xcat.
__global__ __launch_bounds__(256) void k_smax_ctx(
    const float* __restrict__ enc, const float* __restrict__ scores,
    const float* __restrict__ h0, const float* __restrict__ attn_w,
    const float* __restrict__ attn_b, const float* __restrict__ emb,
    const int* __restrict__ idx,
    float* __restrict__ attn_out, float* __restrict__ ctxp,
    float* __restrict__ xcat) {
  __shared__ float red[256];
  __shared__ float aw[S];
  int b = blockIdx.x, sq = blockIdx.y, t = threadIdx.x;
  int lane = t & 63, wv = t >> 6;
  // h_part = dot(h0[b], attn_w[:H]) + attn_b
  const float4* h4 = (const float4*)(h0 + (long long)b * H);
  const float4* w4 = (const float4*)attn_w;
  float4 hv = h4[t], wq = w4[t];
  float p = hv.x * wq.x + hv.y * wq.y + hv.z * wq.z + hv.w * wq.w;
#pragma unroll
  for (int m = 32; m; m >>= 1) p += __shfl_xor(p, m, 64);
  if (lane == 0) red[wv] = p;
  __syncthreads();
  float hp = red[0] + red[1] + red[2] + red[3] + attn_b[0];
  __syncthreads();
  // softmax over the 128 scores
  float sc = (t < S) ? (scores[b * S + t] + hp) : -INFINITY;
  red[t] = sc; __syncthreads();
  for (int off = 128; off; off >>= 1) {
    if (t < off) red[t] = fmaxf(red[t], red[t + off]);
    __syncthreads();
  }
  float mx = red[0]; __syncthreads();
  float e = (t < S) ? __expf(sc - mx) : 0.f;
  red[t] = e; __syncthreads();
  for (int off = 128; off; off >>= 1) {
    if (t < off) red[t] += red[t + off];
    __syncthreads();
  }
  float inv = 1.f / red[0];
  if (t < S) {
    float w = e * inv;
    aw[t] = w;
    if (sq == 0) attn_out[(long long)b * S + t] = w;
  }
  __syncthreads();
  // context partial over s in [sq*16, sq*16+16)
  const float4* e4 = (const float4*)enc;
  float4 a0 = {0.f, 0.f, 0.f, 0.f}, a1 = {0.f, 0.f, 0.f, 0.f};
  int s0 = sq * 16;
#pragma unroll 4
  for (int s = 0; s < 16; s += 2) {
    float4 v0 = e4[(long long)(b * S + s0 + s) * (H / 4) + t];
    float4 v1 = e4[(long long)(b * S + s0 + s + 1) * (H / 4) + t];
    float c0 = aw[s0 + s], c1 = aw[s0 + s + 1];
    a0.x += c0 * v0.x; a0.y += c0 * v0.y; a0.z += c0 * v0.z; a0.w += c0 * v0.w;
    a1.x += c1 * v1.x; a1.y += c1 * v1.y; a1.z += c1 * v1.z; a1.w += c1 * v1.w;
  }
  a0.x += a1.x; a0.y += a1.y; a0.z += a1.z; a0.w += a1.w;
  ((float4*)ctxp)[(long long)(sq * B + b) * (H / 4) + t] = a0;
  if (sq == 0) {   // emb half of xcat
    ((float4*)xcat)[b * 512 + t] =
        ((const float4*)emb)[(long long)idx[b] * 256 + t];
  }
}

// ---- K3: combine 8 context partials -> xcat context half. 64 blocks. -------
__global__ __launch_bounds__(256) void k_xcat_ctx(
    const float* __restrict__ ctxp, float* __restrict__ xcat) {
  int ft = blockIdx.x * 256 + threadIdx.x;   // [0, B*256)
  int b = ft >> 8, hq = ft & 255;
  const float4* c4 = (const float4*)ctxp;
  float4 ctx = c4[(0 * B + b) * 256 + hq];
#pragma unroll
  for (int sq = 1; sq < 8; ++sq) {
    float4 v = c4[(sq * B + b) * 256 + hq];
    ctx.x += v.x; ctx.y += v.y; ctx.z += v.z; ctx.w += v.w;
  }
  ((float4*)xcat)[b * 512 + 256 + hq] = ctx;
}

// ---------------- K6: sum split-K partials, LSTM cell, mask -----------------
__global__ __launch_bounds__(256) void k_lstm(
    const float* __restrict__ part, const float* __restrict__ b_ih,
    const float* __restrict__ b_hh, const float* __restrict__ c0,
    const int* __restrict__ lengths,
    float* __restrict__ h1, float* __restrict__ c1) {
  int ft = blockIdx.x * 256 + threadIdx.x;   // [0, B*H)
  int b = ft >> 10, h = ft & 1023;
  float gs[4] = {0.f, 0.f, 0.f, 0.f};
  for (int ks = 0; ks < 6; ++ks) {
    const float* p = part + (long long)(ks * B + b) * 4096;
#pragma unroll
    for (int q = 0; q < 4; ++q) gs[q] += p[q * H + h];
  }
#pragma unroll
  for (int q = 0; q < 4; ++q) gs[q] += b_ih[q * H + h] + b_hh[q * H + h];
  float ig = 1.f / (1.f + expf(-gs[0]));
  float fg = 1.f / (1.f + expf(-gs[1]));
  float gg = tanhf(gs[2]);
  float og = 1.f / (1.f + expf(-gs[3]));
  float c = fg * c0[ft] + ig * gg;
  float hh = og * tanhf(c);
  if (lengths[b] == 0) { c = 0.f; hh = 0.f; }
  h1[ft] = hh; c1[ft] = c;
}

// ------ K9: combine 500 per-block partials per row -> lc[b] = M + log(L) ----
__global__ __launch_bounds__(256) void k_lsm_comb(
    const float* __restrict__ pm, const float* __restrict__ pl,
    float* __restrict__ lc) {
  __shared__ float red[256];
  int b = blockIdx.x, t = threadIdx.x;
  float v0 = pm[b * 512 + t];                       // t < 256 < 500: valid
  float v1 = (t + 256 < 500) ? pm[b * 512 + t + 256] : -INFINITY;
  red[t] = fmaxf(v0, v1); __syncthreads();
  for (int off = 128; off; off >>= 1) {
    if (t < off) red[t] = fmaxf(red[t], red[t + off]);
    __syncthreads();
  }
  float M = red[0]; __syncthreads();
  float s = pl[b * 512 + t] * __expf(v0 - M);
  if (t + 256 < 500) s += pl[b * 512 + t + 256] * __expf(v1 - M);
  red[t] = s; __syncthreads();
  for (int off = 128; off; off >>= 1) {
    if (t < off) red[t] += red[t + off];
    __syncthreads();
  }
  if (t == 0) lc[b] = M + logf(red[0]);
}

// ---------------- K10: logprobs = logits - lc[b], in place ------------------
__global__ __launch_bounds__(256) void k_lsm_fin(
    float* __restrict__ logits, const float* __restrict__ lc) {
  int fi = blockIdx.x * 256 + threadIdx.x;   // float4 index, < 512000
  float4* p = (float4*)logits;
  float4 x = p[fi];
  float c = lc[fi / 8000];                   // 8000 float4 per row
  x.x -= c; x.y -= c; x.z -= c; x.w -= c;
  p[fi] = x;
}

extern "C" void kernel_launch(void* const* d_in, const int* in_sizes, int n_in,
                              void* d_out, int out_size, void* d_ws, size_t ws_size,
                              hipStream_t stream) {
  const int*   input_batch = (const int*)d_in[0];
  const float* prev_h = (const float*)d_in[1];
  const float* prev_c = (const float*)d_in[2];
  const float* enc    = (const float*)d_in[3];
  const int*   lengths= (const int*)d_in[4];
  const float* emb    = (const float*)d_in[5];
  const float* attn_w = (const float*)d_in[6];
  const float* attn_b = (const float*)d_in[7];
  const float* W_ih   = (const float*)d_in[8];
  const float* W_hh   = (const float*)d_in[9];
  const float* b_ih   = (const float*)d_in[10];
  const float* b_hh   = (const float*)d_in[11];
  const float* W_out  = (const float*)d_in[12];
  const float* b_out  = (const float*)d_in[13];

  float* out = (float*)d_out;
  float* ws  = (float*)d_ws;

  float* scores = ws + WS_SCORES;
  float* xcat   = ws + WS_XCAT;
  float* part   = ws + WS_PART;
  float* ctxp   = ws + WS_CTXP;
  float* pm     = ws + WS_PM;
  float* pl     = ws + WS_PL;
  float* lc     = ws + WS_LC;

  float* logits = out;             // logprobs region, used as logits scratch
  float* h1     = out + OUT_H1;
  float* c1     = out + OUT_C1;
  float* attn   = out + OUT_ATTN;

  // attention: full-BW scores pass, then redundant-softmax + ctx partials
  k_scores  <<<dim3(B * S / 4), 256, 0, stream>>>(enc, attn_w, scores);
  k_smax_ctx<<<dim3(B, 8),      256, 0, stream>>>(enc, scores, prev_h, attn_w,
                                                  attn_b, emb, input_batch,
                                                  attn, ctxp, xcat);
  k_xcat_ctx<<<dim3(B * 256 / 256), 256, 0, stream>>>(ctxp, xcat);

  // gates = xcat @ W_ih^T (split-K 4) + h0 @ W_hh^T (split-K 2) -> 6 partials
  k_gates_mfma<<<dim3(64, 6), 256, 0, stream>>>(W_ih, xcat, W_hh, prev_h, part);
  k_lstm<<<dim3(B * H / 256), 256, 0, stream>>>(part, b_ih, b_hh, prev_c,
                                                lengths, h1, c1);

  // logits = h1 @ W_out^T + b_out, fused log-softmax partials
  k_logits_mfma<<<dim3(V / 64), 256, 0, stream>>>(W_out, h1, logits, b_out, pm, pl);

  // log-softmax over V, in place
  k_lsm_comb<<<dim3(B), 256, 0, stream>>>(pm, pl, lc);
  k_lsm_fin <<<dim3(B * V / 4 / 256), 256, 0, stream>>>(logits, lc);
}